// Round 22
// baseline (331.917 us; speedup 1.0000x reference)
//
#include <hip/hip_runtime.h>
#include <hip/hip_bf16.h>
#include <math.h>

// ---------------------------------------------------------------------------
// VaryMambaModel: batch=1, L=128
//   PRE_D=2048, D=4096, N=64, K=4, DI1=4096, DI2=8192, DTR1=128, DTR2=256
// Round 21: producer/consumer weight GEMM v2 — ring 3->4 slots, publish-lag
// 1->2 (vmcnt(8)): each producer keeps 2 chunks (8 loads) in flight instead
// of 1, ~1.7x in-flight bytes. Protocol generalizes the validated round-20
// one (lane-0-guarded monotonic counters). Consumer compute byte-identical.
// ---------------------------------------------------------------------------

typedef __attribute__((ext_vector_type(8))) short short8_t;   // 8 bf16
typedef __attribute__((ext_vector_type(4))) float f32x4;

__device__ __forceinline__ float sigmoidf_(float x) {
  return 1.0f / (1.0f + __expf(-x));
}
__device__ __forceinline__ float softplusf_(float x) {
  return fmaxf(x, 0.0f) + log1pf(expf(-fabsf(x)));
}
__device__ __forceinline__ void splitbf(float f, ushort& h, ushort& lo) {
  __hip_bfloat16 hb = __float2bfloat16(f);
  h = *reinterpret_cast<ushort*>(&hb);
  float hf = __bfloat162float(hb);
  __hip_bfloat16 lb = __float2bfloat16(f - hf);
  lo = *reinterpret_cast<ushort*>(&lb);
}
// truncation split: f = h + r exactly; lo = trunc_bf16(r)
__device__ __forceinline__ void tsplit(float f, ushort& h, ushort& lo) {
  unsigned u = __float_as_uint(f);
  h = (ushort)(u >> 16);
  float r = f - __uint_as_float(u & 0xFFFF0000u);
  lo = (ushort)(__float_as_uint(r) >> 16);
}
// packed layout (per 32-k chunk, 8192 ushorts): [hl][kb=(k>>3)&3][row][k&7]
__device__ __forceinline__ size_t poff(int l, int d) {
  return (size_t)(d >> 5) * 8192 + (size_t)((d >> 3) & 3) * 1024 +
         (size_t)l * 8 + (d & 7);
}
// 16B/lane global->LDS DMA (linear dest: base + lane*16)
__device__ __forceinline__ void g2l16(const float* g, float* lp) {
  __builtin_amdgcn_global_load_lds(
      (const __attribute__((address_space(1))) unsigned int*)g,
      (__attribute__((address_space(3))) unsigned int*)lp, 16, 0, 0);
}

// ---------------- prep: x0 = pe + cond*to_cond_w + to_cond_b -> packed ------
__global__ __launch_bounds__(256) void k_prep(const float* __restrict__ pe,
                                              const float* __restrict__ cw,
                                              const float* __restrict__ cb,
                                              const float* __restrict__ cond,
                                              ushort* __restrict__ xp) {
  int i = blockIdx.x * 256 + threadIdx.x;  // 128*2048
  int d = i & 2047;
  int l = i >> 11;
  float v = pe[i] + cond[0] * cw[d] + cb[d];
  ushort h, lo;
  splitbf(v, h, lo);
  size_t o = poff(l, d);
  xp[o] = h;
  xp[o + 4096] = lo;
}

// ---------------- producer/consumer weight GEMM v2 (4-ring, lag-2) ----------
// Tile 128m x 128n, 512 thr = 8 waves. Waves 4-7: producers (wave p stages
// rows 32p..32p+31 of each 32k chunk via 4x g2l16, 4-deep ring, vmcnt(8)
// publish-lag-2). Waves 0-3: consumers (2x2, 64m x 64n) — champion verbatim.
#define KWS 32
__global__ __launch_bounds__(512, 2) void k_gemmWPC(const ushort* __restrict__ Ap,
                                                    const float* __restrict__ W, int ldw,
                                                    float* __restrict__ P,
                                                    int N, int Ks) {
  __shared__ float ring[4][128][32];   // 64 KB
  __shared__ int rdy[4];
  __shared__ int cns[4];

  const int n0   = blockIdx.x * 128;
  const int s    = blockIdx.z;
  const int kbeg = s * Ks;
  const int t    = threadIdx.x;
  const int l    = t & 63;
  const int w    = t >> 6;          // 0..7
  const int nIter = Ks / KWS;       // >= 4 by launch policy

  if (t < 4) { rdy[t] = 0; cns[t] = 0; }
  __syncthreads();

  if (w >= 4) {
    // ================= PRODUCER (wave p = w-4) =================
    const int p = w - 4;
    const int grow = l >> 3;
    const int gg   = (l & 7) ^ (grow & 7);
    const float* gW[4];
#pragma unroll
    for (int i = 0; i < 4; ++i)
      gW[i] = W + (size_t)(n0 + 32 * p + 8 * i + grow) * ldw + kbeg + gg * 4;
    float* ldst[4];
#pragma unroll
    for (int i = 0; i < 4; ++i)
      ldst[i] = &ring[0][0][0] + (32 * p + 8 * i) * 32;

    volatile int* vcns = cns;
    int slot = 0;
    for (int j = 0; j < nIter; ++j) {
      if (j >= 4) {
        const int tgt = 4 * (j / 4);           // chunk j-4 fully consumed
        while (vcns[slot] < tgt) __builtin_amdgcn_s_sleep(2);
        __builtin_amdgcn_sched_barrier(0);
      }
#pragma unroll
      for (int i = 0; i < 4; ++i)
        g2l16(gW[i] + (size_t)j * KWS, ldst[i] + slot * 128 * 32);
      if (j >= 2) {
        asm volatile("s_waitcnt vmcnt(8)" ::: "memory");   // chunk j-2 landed
        __builtin_amdgcn_sched_barrier(0);
        if (l == 0) atomicAdd(&rdy[(j - 2) & 3], 1);
      }
      slot = (slot + 1) & 3;
    }
    // tail: drain remaining two chunks
    asm volatile("s_waitcnt vmcnt(4)" ::: "memory");
    __builtin_amdgcn_sched_barrier(0);
    if (l == 0) atomicAdd(&rdy[(nIter - 2) & 3], 1);
    asm volatile("s_waitcnt vmcnt(0)" ::: "memory");
    __builtin_amdgcn_sched_barrier(0);
    if (l == 0) atomicAdd(&rdy[(nIter - 1) & 3], 1);
    return;
  }

  // ================= CONSUMER (wave w = 0..3) =================
  const int wm = w >> 1;
  const int wn = w & 1;
  const int lr = l & 15;
  const int lg = l >> 4;

  f32x4 acc[4][4];
#pragma unroll
  for (int mi = 0; mi < 4; ++mi)
#pragma unroll
    for (int ni = 0; ni < 4; ++ni) acc[mi][ni] = (f32x4)(0.0f);

  const ushort* pA0 = Ap + (size_t)(kbeg >> 5) * 8192;
  const int arow = 64 * wm + lr;
  const int rsw  = lr & 7;
  volatile int* vrdy = rdy;

  int slot = 0;
  for (int j = 0; j < nIter; ++j) {
    // A fragments for this chunk (overlap the spin)
    const ushort* pAj = pA0 + (size_t)j * 8192;
    short8_t ah[4], al[4];
#pragma unroll
    for (int mi = 0; mi < 4; ++mi) {
      const size_t fo = (size_t)lg * 1024 + (size_t)(arow + 16 * mi) * 8;
      ah[mi] = *(const short8_t*)(pAj + fo);
      al[mi] = *(const short8_t*)(pAj + 4096 + fo);
    }
    const int tgt = 4 * (j / 4 + 1);           // chunk j fully published
    while (vrdy[slot] < tgt) __builtin_amdgcn_s_sleep(2);
    __builtin_amdgcn_sched_barrier(0);

    const float* Wb = &ring[slot][0][0];
#pragma unroll
    for (int ni = 0; ni < 4; ++ni) {
      const int r = 64 * wn + 16 * ni + lr;
      const float4 v0 = *(const float4*)(Wb + r * 32 + (((2 * lg) ^ rsw) * 4));
      const float4 v1 = *(const float4*)(Wb + r * 32 + (((2 * lg + 1) ^ rsw) * 4));
      short8_t bh, bl;
      {
        const float f8[8] = {v0.x, v0.y, v0.z, v0.w, v1.x, v1.y, v1.z, v1.w};
#pragma unroll
        for (int e = 0; e < 8; ++e) {
          ushort h, lo;
          tsplit(f8[e], h, lo);
          bh[e] = (short)h;
          bl[e] = (short)lo;
        }
      }
#pragma unroll
      for (int mi = 0; mi < 4; ++mi) {
        acc[mi][ni] = __builtin_amdgcn_mfma_f32_16x16x32_bf16(ah[mi], bh, acc[mi][ni], 0, 0, 0);
        acc[mi][ni] = __builtin_amdgcn_mfma_f32_16x16x32_bf16(al[mi], bh, acc[mi][ni], 0, 0, 0);
        acc[mi][ni] = __builtin_amdgcn_mfma_f32_16x16x32_bf16(ah[mi], bl, acc[mi][ni], 0, 0, 0);
      }
    }
    asm volatile("s_waitcnt lgkmcnt(0)" ::: "memory");  // B reads retired
    __builtin_amdgcn_sched_barrier(0);
    if (l == 0) atomicAdd(&cns[slot], 1);
    slot = (slot + 1) & 3;
  }

  float* Pd = P + (size_t)s * 128 * N + n0 + 64 * wn;
#pragma unroll
  for (int mi = 0; mi < 4; ++mi)
#pragma unroll
    for (int ni = 0; ni < 4; ++ni) {
#pragma unroll
      for (int jj = 0; jj < 4; ++jj) {
        const int m = 64 * wm + 16 * mi + 4 * lg + jj;
        Pd[(size_t)m * N + 16 * ni + lr] = acc[mi][ni][jj];
      }
    }
}

// ---------------- small-K GEMM (round-8): P[s] = X * W^T --------------------
#define KSTEP 32
__global__ __launch_bounds__(256, 2) void k_gemm(const ushort* __restrict__ Ap,
                                                 const float* __restrict__ W, int ldw,
                                                 float* __restrict__ P,
                                                 int N, int Ks) {
  __shared__ ushort Ws[2][2][4][128][8];   // 32 KB

  const int n0   = blockIdx.x * 128;
  const int s    = blockIdx.z;
  const int kbeg = s * Ks;
  const int t    = threadIdx.x;
  const int l    = t & 63;
  const int w    = t >> 6;
  const int wm   = w >> 1;
  const int wn   = w & 1;
  const int lr   = l & 15;
  const int lg   = l >> 4;

  f32x4 acc[4][4];
#pragma unroll
  for (int mi = 0; mi < 4; ++mi)
#pragma unroll
    for (int ni = 0; ni < 4; ++ni) acc[mi][ni] = (f32x4)(0.0f);

  const int srow = t >> 3;
  const int sk16 = t & 7;
  const int skb  = sk16 >> 1;
  const int se0  = (sk16 & 1) * 4;
  const float* pWg = W + (size_t)(n0 + srow) * ldw + kbeg + sk16 * 4;

  const ushort* pAc = Ap + (size_t)(kbeg >> 5) * 8192;
  const int arow = 64 * wm + lr;
  const int brow = 64 * wn + lr;

  const int nIter = Ks / KSTEP;
  float4 wv[4];

#pragma unroll
  for (int r = 0; r < 4; ++r)
    wv[r] = *(const float4*)(pWg + (size_t)(r * 32) * ldw);
#pragma unroll
  for (int r = 0; r < 4; ++r) {
    ushort4 h4, l4;
    splitbf(wv[r].x, h4.x, l4.x); splitbf(wv[r].y, h4.y, l4.y);
    splitbf(wv[r].z, h4.z, l4.z); splitbf(wv[r].w, h4.w, l4.w);
    *(ushort4*)&Ws[0][0][skb][srow + 32 * r][se0] = h4;
    *(ushort4*)&Ws[0][1][skb][srow + 32 * r][se0] = l4;
  }
  __syncthreads();

  for (int j = 0; j < nIter; ++j) {
    const int bi = j & 1;
    const bool more = (j + 1 < nIter);

    const ushort* pAj = pAc + (size_t)j * 8192;
    short8_t ah[4], al[4];
#pragma unroll
    for (int mi = 0; mi < 4; ++mi) {
      const size_t fo = (size_t)lg * 1024 + (size_t)(arow + 16 * mi) * 8;
      ah[mi] = *(const short8_t*)(pAj + fo);
      al[mi] = *(const short8_t*)(pAj + 4096 + fo);
    }
    if (more) {
      const size_t ko = (size_t)(j + 1) * KSTEP;
#pragma unroll
      for (int r = 0; r < 4; ++r)
        wv[r] = *(const float4*)(pWg + ko + (size_t)(r * 32) * ldw);
    }
    short8_t bh[4], bl[4];
#pragma unroll
    for (int ni = 0; ni < 4; ++ni) {
      bh[ni] = *(const short8_t*)&Ws[bi][0][lg][brow + 16 * ni][0];
      bl[ni] = *(const short8_t*)&Ws[bi][1][lg][brow + 16 * ni][0];
    }
#pragma unroll
    for (int mi = 0; mi < 4; ++mi)
#pragma unroll
      for (int ni = 0; ni < 4; ++ni) {
        acc[mi][ni] = __builtin_amdgcn_mfma_f32_16x16x32_bf16(ah[mi], bh[ni], acc[mi][ni], 0, 0, 0);
        acc[mi][ni] = __builtin_amdgcn_mfma_f32_16x16x32_bf16(al[mi], bh[ni], acc[mi][ni], 0, 0, 0);
        acc[mi][ni] = __builtin_amdgcn_mfma_f32_16x16x32_bf16(ah[mi], bl[ni], acc[mi][ni], 0, 0, 0);
      }
    if (more) {
#pragma unroll
      for (int r = 0; r < 4; ++r) {
        ushort4 h4, l4;
        splitbf(wv[r].x, h4.x, l4.x); splitbf(wv[r].y, h4.y, l4.y);
        splitbf(wv[r].z, h4.z, l4.z); splitbf(wv[r].w, h4.w, l4.w);
        *(ushort4*)&Ws[bi ^ 1][0][skb][srow + 32 * r][se0] = h4;
        *(ushort4*)&Ws[bi ^ 1][1][skb][srow + 32 * r][se0] = l4;
      }
    }
    __syncthreads();
  }

  float* Pd = P + (size_t)s * 128 * N + n0 + 64 * wn;
#pragma unroll
  for (int mi = 0; mi < 4; ++mi)
#pragma unroll
    for (int ni = 0; ni < 4; ++ni) {
#pragma unroll
      for (int jj = 0; jj < 4; ++jj) {
        const int m = 64 * wm + 16 * mi + 4 * lg + jj;
        Pd[(size_t)m * N + 16 * ni + lr] = acc[mi][ni][jj];
      }
    }
}

// ---------------- reduce partials + epilogues -------------------------------
__global__ __launch_bounds__(256) void k_reduce(const float* __restrict__ P,
                                                float* __restrict__ Y,
                                                ushort* __restrict__ Yp,
                                                int MN, int N, int S, int ep,
                                                const float* __restrict__ bias) {
  int i = (blockIdx.x * 256 + threadIdx.x) * 4;
  if (i >= MN) return;
  float4 v = *(const float4*)&P[i];
  for (int s = 1; s < S; ++s) {
    float4 p = *(const float4*)&P[(size_t)s * MN + i];
    v.x += p.x; v.y += p.y; v.z += p.z; v.w += p.w;
  }
  int n = i % N;
  int l = i / N;
  if (ep & 1) {
    const float4 b = *(const float4*)&bias[n];
    v.x = softplusf_(v.x + b.x);
    v.y = softplusf_(v.y + b.y);
    v.z = softplusf_(v.z + b.z);
    v.w = softplusf_(v.w + b.w);
  }
  if (ep & 4) *(float4*)&Y[i] = v;
  if (ep & 2) {
    ushort4 h4, l4;
    splitbf(v.x, h4.x, l4.x);
    splitbf(v.y, h4.y, l4.y);
    splitbf(v.z, h4.z, l4.z);
    splitbf(v.w, h4.w, l4.w);
    size_t o = poff(l, n);
    *(ushort4*)&Yp[o] = h4;
    *(ushort4*)&Yp[o + 4096] = l4;
  }
}

__global__ __launch_bounds__(256) void k_reduceA(const float* __restrict__ P,
                                                 float* __restrict__ Y, int MN) {
  int g = blockIdx.y;
  int i = (blockIdx.x * 256 + threadIdx.x) * 4;
  if (i >= MN) return;
  const float* Pp = P + (size_t)g * 8 * MN;
  float4 v = *(const float4*)&Pp[i];
  for (int s = 1; s < 8; ++s) {
    float4 p = *(const float4*)&Pp[(size_t)s * MN + i];
    v.x += p.x; v.y += p.y; v.z += p.z; v.w += p.w;
  }
  *(float4*)&Y[(size_t)g * MN + i] = v;
}

// ---------------- depthwise causal conv (K=4) + silu + packed split ---------
__global__ __launch_bounds__(256) void k_conv_silu(const float* __restrict__ xz,
                                                   const float* __restrict__ cw,
                                                   const float* __restrict__ cb,
                                                   float* __restrict__ xc,
                                                   ushort* __restrict__ xcp,
                                                   int DI, int lg2DI) {
  int i = blockIdx.x * 256 + threadIdx.x;  // over 128*DI
  int l = i >> lg2DI;
  int d = i & (DI - 1);
  const float4 w = *(const float4*)&cw[d * 4];
  const float* xr = xz + d;
  int ld = 2 * DI;
  float s = cb[d];
  s += w.w * xr[l * ld];
  if (l >= 1) s += w.z * xr[(l - 1) * ld];
  if (l >= 2) s += w.y * xr[(l - 2) * ld];
  if (l >= 3) s += w.x * xr[(l - 3) * ld];
  float v = s * sigmoidf_(s);
  xc[i] = v;
  ushort h, lo;
  splitbf(v, h, lo);
  size_t o = poff(l, d);
  xcp[o] = h;
  xcp[o + 4096] = lo;
}

// ---------------- selective scan + fused gate: packed output ----------------
__global__ __launch_bounds__(256) void k_scan(const float* __restrict__ dt,
                                              const float* __restrict__ xc,
                                              const float* __restrict__ dbc,
                                              const float* __restrict__ A_log,
                                              const float* __restrict__ Dp,
                                              const float* __restrict__ xz,
                                              ushort* __restrict__ yp,
                                              int DI, int DTR) {
  __shared__ float cs[4][32][65];
  const int wid = threadIdx.x >> 6;
  const int n   = threadIdx.x & 63;
  const int d   = blockIdx.x * 4 + wid;
  const int du  = __builtin_amdgcn_readfirstlane(d);
  const float A  = -__expf(A_log[(size_t)du * 64 + n]);
  const float Dd = Dp[du];
  const int ldbc = DTR + 128;
  const float* Bp = dbc + DTR + n;
  const float* Cp = dbc + DTR + 64 + n;
  float h = 0.0f;
  for (int l0 = 0; l0 < 128; l0 += 32) {
#pragma unroll 8
    for (int l = l0; l < l0 + 32; ++l) {
      float dtv = dt[(size_t)l * DI + du];
      float xcv = xc[(size_t)l * DI + du];
      float dA  = __expf(dtv * A);
      float bx  = dtv * xcv;
      h = fmaf(dA, h, bx * Bp[(size_t)l * ldbc]);
      cs[wid][l - l0][n] = h * Cp[(size_t)l * ldbc];
    }
    __syncthreads();
    const int r = n & 31, hf = n >> 5;
    float ssum = 0.0f;
#pragma unroll
    for (int j = 0; j < 32; ++j) ssum += cs[wid][r][hf * 32 + j];
    ssum += __shfl_xor(ssum, 32, 64);
    if (n < 32) {
      int ll = l0 + r;
      float xcv = xc[(size_t)ll * DI + du];
      float yv  = ssum + xcv * Dd;
      float z   = xz[(size_t)ll * 2 * DI + DI + du];
      float v   = yv * (z * sigmoidf_(z));
      ushort hh, lo;
      splitbf(v, hh, lo);
      size_t o = poff(ll, du);
      yp[o] = hh;
      yp[o + 4096] = lo;
    }
    __syncthreads();
  }
}

// ---------------------------------------------------------------------------
struct GemmCtx {
  float* part;
  float* part2;
  long long cap;
};

static inline void reduce_stage(float* dstF, ushort* dstP, int N, int S, int ep,
                                const float* bias, const GemmCtx& cx,
                                hipStream_t stream) {
  const int MN = 128 * N;
  const int rb = (MN / 4 + 255) / 256;
  if (S <= 32) {
    k_reduce<<<rb, 256, 0, stream>>>(cx.part, dstF, dstP, MN, N, S, ep, bias);
  } else {
    k_reduceA<<<dim3(rb, S / 8), 256, 0, stream>>>(cx.part, cx.part2, MN);
    k_reduce<<<rb, 256, 0, stream>>>(cx.part2, dstF, dstP, MN, N, S / 8, ep, bias);
  }
}

// small-K GEMM path (x_proj / dt_proj)
static inline void gemmS(const ushort* Ap, const float* W, int ldw,
                         float* dstF, ushort* dstP,
                         int N, int K, int Sdes, int ep,
                         const float* bias, const GemmCtx& cx, hipStream_t stream) {
  int S = Sdes;
  if (S > K / KSTEP) S = K / KSTEP;
  if (S < 1) S = 1;
  while (S > 1 && (long long)S * 128 * N > cx.cap) S >>= 1;
  const int Ks = K / S;
  const bool direct = (S == 1 && ep == 4);
  dim3 g(N / 128, 1, S);
  k_gemm<<<g, 256, 0, stream>>>(Ap, W, ldw, direct ? dstF : cx.part, N, Ks);
  if (!direct) reduce_stage(dstF, dstP, N, S, ep, bias, cx, stream);
}

// weight-heavy GEMM path (in_proj / out_proj) — producer/consumer v2
static inline void gemmW(const ushort* Ap, const float* W, int ldw,
                         float* dstF, ushort* dstP,
                         int N, int K, int Sdes, int ep,
                         const float* bias, const GemmCtx& cx, hipStream_t stream) {
  int S = Sdes;
  if (S > K / (4 * KWS)) S = K / (4 * KWS);   // keep nIter >= 4
  if (S < 1) S = 1;
  while (S > 1 && (long long)S * 128 * N > cx.cap) S >>= 1;
  const int Ks = K / S;
  const bool direct = (S == 1 && ep == 4);
  dim3 g(N / 128, 1, S);
  k_gemmWPC<<<g, 512, 0, stream>>>(Ap, W, ldw, direct ? dstF : cx.part, N, Ks);
  if (!direct) reduce_stage(dstF, dstP, N, S, ep, bias, cx, stream);
}

extern "C" void kernel_launch(void* const* d_in, const int* in_sizes, int n_in,
                              void* d_out, int out_size, void* d_ws, size_t ws_size,
                              hipStream_t stream) {
  const float* pe        = (const float*)d_in[0];
  const float* to_cond_w = (const float*)d_in[1];
  const float* to_cond_b = (const float*)d_in[2];
  const float* condition = (const float*)d_in[3];
  const int o = (in_sizes[4] == 1) ? 5 : 4;
  const float* m1_in_proj  = (const float*)d_in[o + 0];
  const float* m1_conv_w   = (const float*)d_in[o + 1];
  const float* m1_conv_b   = (const float*)d_in[o + 2];
  const float* m1_x_proj   = (const float*)d_in[o + 3];
  const float* m1_dt_w     = (const float*)d_in[o + 4];
  const float* m1_dt_b     = (const float*)d_in[o + 5];
  const float* m1_A_log    = (const float*)d_in[o + 6];
  const float* m1_D        = (const float*)d_in[o + 7];
  const float* m1_out_proj = (const float*)d_in[o + 8];
  const float* m2_in_proj  = (const float*)d_in[o + 9];
  const float* m2_conv_w   = (const float*)d_in[o + 10];
  const float* m2_conv_b   = (const float*)d_in[o + 11];
  const float* m2_x_proj   = (const float*)d_in[o + 12];
  const float* m2_dt_w     = (const float*)d_in[o + 13];
  const float* m2_dt_b     = (const float*)d_in[o + 14];
  const float* m2_A_log    = (const float*)d_in[o + 15];
  const float* m2_D        = (const float*)d_in[o + 16];
  const float* m2_out_proj = (const float*)d_in[o + 17];

  float* ws = (float*)d_ws;
  float*  xz   = ws;                        // 2,097,152
  float*  xc   = ws + 2097152;              // 1,048,576
  float*  dbc  = ws + 3145728;              //    49,152
  float*  dtb  = ws + 3194880;              // 1,048,576
  ushort* x0p  = (ushort*)(ws + 5292032);   //   262,144 f (hi+lo packed)
  ushort* xcp  = (ushort*)(ws + 5554176);   // 1,048,576 f
  ushort* dbcp = (ushort*)(ws + 6602752);   //    49,152 f
  ushort* ybp  = (ushort*)(ws + 6651904);   // 1,048,576 f
  ushort* midp = (ushort*)(ws + 7700480);   //   262,144 f
  float*  part2 = ws + 7962624;             //   786,432
  float*  part  = ws + 8749056;             // rest

  GemmCtx cx;
  cx.part = part;
  cx.part2 = part2;
  cx.cap = (long long)(ws_size / 4) - 8749056;
  if (cx.cap < 0) cx.cap = 0;

  k_prep<<<1024, 256, 0, stream>>>(pe, to_cond_w, to_cond_b, condition, x0p);

  // ---------------- mamba block 1: DI=4096, DTR=128 ----------------
  gemmW(x0p, m1_in_proj, 2048, xz, nullptr, 8192, 2048, 8, 4, nullptr, cx, stream);   // 512 blk
  k_conv_silu<<<(128 * 4096) / 256, 256, 0, stream>>>(xz, m1_conv_w, m1_conv_b,
                                                      xc, xcp, 4096, 12);
  gemmS(xcp, m1_x_proj, 4096, dbc, dbcp, 256, 4096, 128, 6, nullptr, cx, stream);
  gemmS(dbcp, m1_dt_w, 128, dtb, nullptr, 4096, 128, 4, 5, m1_dt_b, cx, stream);
  k_scan<<<1024, 256, 0, stream>>>(dtb, xc, dbc, m1_A_log, m1_D, xz, ybp, 4096, 128);
  gemmW(ybp, m1_out_proj, 4096, nullptr, midp, 2048, 4096, 32, 2, nullptr, cx, stream); // 512 blk

  // ---------------- mamba block 2: DI=8192, DTR=256 ----------------
  gemmW(midp, m2_in_proj, 2048, xz, nullptr, 16384, 2048, 4, 4, nullptr, cx, stream); // 512 blk
  k_conv_silu<<<(128 * 8192) / 256, 256, 0, stream>>>(xz, m2_conv_w, m2_conv_b,
                                                      xc, xcp, 8192, 13);
  gemmS(xcp, m2_x_proj, 8192, dbc, dbcp, 384, 8192, 128, 6, nullptr, cx, stream);
  gemmS(dbcp, m2_dt_w, 256, dtb, nullptr, 8192, 256, 4, 5, m2_dt_b, cx, stream);
  k_scan<<<2048, 256, 0, stream>>>(dtb, xc, dbc, m2_A_log, m2_D, xz, ybp, 8192, 256);
  gemmW(ybp, m2_out_proj, 8192, (float*)d_out, nullptr, 4096, 8192, 16, 4, nullptr, cx, stream); // 512 blk
}

// Round 23
// 329.627 us; speedup vs baseline: 1.0069x; 1.0069x over previous
//
#include <hip/hip_runtime.h>
#include <hip/hip_bf16.h>
#include <math.h>

// ---------------------------------------------------------------------------
// VaryMambaModel: batch=1, L=128
//   PRE_D=2048, D=4096, N=64, K=4, DI1=4096, DI2=8192, DTR1=128, DTR2=256
// Round 22: FINAL — revert to round-20 producer/consumer champion (329.6 us).
// 3-deep ring, vmcnt(4) publish-lag-1, lane-0-guarded monotonic counters.
// Round-21's 4-ring/lag-2 was neutral (consumer-paced) and is discarded.
// Trajectory: 3902 -> 669 -> 500 -> 343 -> 329.6 us.
// ---------------------------------------------------------------------------

typedef __attribute__((ext_vector_type(8))) short short8_t;   // 8 bf16
typedef __attribute__((ext_vector_type(4))) float f32x4;

__device__ __forceinline__ float sigmoidf_(float x) {
  return 1.0f / (1.0f + __expf(-x));
}
__device__ __forceinline__ float softplusf_(float x) {
  return fmaxf(x, 0.0f) + log1pf(expf(-fabsf(x)));
}
__device__ __forceinline__ void splitbf(float f, ushort& h, ushort& lo) {
  __hip_bfloat16 hb = __float2bfloat16(f);
  h = *reinterpret_cast<ushort*>(&hb);
  float hf = __bfloat162float(hb);
  __hip_bfloat16 lb = __float2bfloat16(f - hf);
  lo = *reinterpret_cast<ushort*>(&lb);
}
// truncation split: f = h + r exactly; lo = trunc_bf16(r)
__device__ __forceinline__ void tsplit(float f, ushort& h, ushort& lo) {
  unsigned u = __float_as_uint(f);
  h = (ushort)(u >> 16);
  float r = f - __uint_as_float(u & 0xFFFF0000u);
  lo = (ushort)(__float_as_uint(r) >> 16);
}
// packed layout (per 32-k chunk, 8192 ushorts): [hl][kb=(k>>3)&3][row][k&7]
__device__ __forceinline__ size_t poff(int l, int d) {
  return (size_t)(d >> 5) * 8192 + (size_t)((d >> 3) & 3) * 1024 +
         (size_t)l * 8 + (d & 7);
}
// 16B/lane global->LDS DMA (linear dest: base + lane*16)
__device__ __forceinline__ void g2l16(const float* g, float* lp) {
  __builtin_amdgcn_global_load_lds(
      (const __attribute__((address_space(1))) unsigned int*)g,
      (__attribute__((address_space(3))) unsigned int*)lp, 16, 0, 0);
}

// ---------------- prep: x0 = pe + cond*to_cond_w + to_cond_b -> packed ------
__global__ __launch_bounds__(256) void k_prep(const float* __restrict__ pe,
                                              const float* __restrict__ cw,
                                              const float* __restrict__ cb,
                                              const float* __restrict__ cond,
                                              ushort* __restrict__ xp) {
  int i = blockIdx.x * 256 + threadIdx.x;  // 128*2048
  int d = i & 2047;
  int l = i >> 11;
  float v = pe[i] + cond[0] * cw[d] + cb[d];
  ushort h, lo;
  splitbf(v, h, lo);
  size_t o = poff(l, d);
  xp[o] = h;
  xp[o + 4096] = lo;
}

// ---------------- producer/consumer weight GEMM (round-20) ------------------
// Tile 128m x 128n, 512 thr = 8 waves. Waves 4-7: producers (wave p stages
// rows 32p..32p+31 of each 32k chunk via 4x g2l16, 3-deep ring). Waves 0-3:
// consumers (2x2, 64m x 64n each). Lane-0-guarded monotonic counters.
#define KWS 32
__global__ __launch_bounds__(512, 2) void k_gemmWPC(const ushort* __restrict__ Ap,
                                                    const float* __restrict__ W, int ldw,
                                                    float* __restrict__ P,
                                                    int N, int Ks) {
  __shared__ float ring[3][128][32];   // 48 KB
  __shared__ int rdy[3];
  __shared__ int cns[3];

  const int n0   = blockIdx.x * 128;
  const int s    = blockIdx.z;
  const int kbeg = s * Ks;
  const int t    = threadIdx.x;
  const int l    = t & 63;
  const int w    = t >> 6;          // 0..7
  const int nIter = Ks / KWS;

  if (t < 3) { rdy[t] = 0; cns[t] = 0; }
  __syncthreads();

  if (w >= 4) {
    // ================= PRODUCER (wave p = w-4) =================
    const int p = w - 4;
    const int grow = l >> 3;
    const int gg   = (l & 7) ^ (grow & 7);
    const float* gW[4];
#pragma unroll
    for (int i = 0; i < 4; ++i)
      gW[i] = W + (size_t)(n0 + 32 * p + 8 * i + grow) * ldw + kbeg + gg * 4;
    float* ldst[4];
#pragma unroll
    for (int i = 0; i < 4; ++i)
      ldst[i] = &ring[0][0][0] + (32 * p + 8 * i) * 32;

    volatile int* vcns = cns;
    int slot = 0;
    for (int j = 0; j < nIter; ++j) {
      if (j >= 3) {
        const int tgt = 4 * (j / 3);           // chunk j-3 fully consumed
        while (vcns[slot] < tgt) __builtin_amdgcn_s_sleep(2);
        __builtin_amdgcn_sched_barrier(0);
      }
#pragma unroll
      for (int i = 0; i < 4; ++i)
        g2l16(gW[i] + (size_t)j * KWS, ldst[i] + slot * 128 * 32);
      if (j >= 1) {
        asm volatile("s_waitcnt vmcnt(4)" ::: "memory");   // chunk j-1 landed
        __builtin_amdgcn_sched_barrier(0);
        if (l == 0) atomicAdd(&rdy[(slot == 0) ? 2 : slot - 1], 1);
      }
      slot = (slot == 2) ? 0 : slot + 1;
    }
    asm volatile("s_waitcnt vmcnt(0)" ::: "memory");
    __builtin_amdgcn_sched_barrier(0);
    if (l == 0) atomicAdd(&rdy[(nIter - 1) % 3], 1);
    return;
  }

  // ================= CONSUMER (wave w = 0..3) =================
  const int wm = w >> 1;
  const int wn = w & 1;
  const int lr = l & 15;
  const int lg = l >> 4;

  f32x4 acc[4][4];
#pragma unroll
  for (int mi = 0; mi < 4; ++mi)
#pragma unroll
    for (int ni = 0; ni < 4; ++ni) acc[mi][ni] = (f32x4)(0.0f);

  const ushort* pA0 = Ap + (size_t)(kbeg >> 5) * 8192;
  const int arow = 64 * wm + lr;
  const int rsw  = lr & 7;
  volatile int* vrdy = rdy;

  int slot = 0;
  for (int j = 0; j < nIter; ++j) {
    // A fragments for this chunk (overlap the spin)
    const ushort* pAj = pA0 + (size_t)j * 8192;
    short8_t ah[4], al[4];
#pragma unroll
    for (int mi = 0; mi < 4; ++mi) {
      const size_t fo = (size_t)lg * 1024 + (size_t)(arow + 16 * mi) * 8;
      ah[mi] = *(const short8_t*)(pAj + fo);
      al[mi] = *(const short8_t*)(pAj + 4096 + fo);
    }
    const int tgt = 4 * (j / 3 + 1);           // chunk j fully published
    while (vrdy[slot] < tgt) __builtin_amdgcn_s_sleep(2);
    __builtin_amdgcn_sched_barrier(0);

    const float* Wb = &ring[slot][0][0];
#pragma unroll
    for (int ni = 0; ni < 4; ++ni) {
      const int r = 64 * wn + 16 * ni + lr;
      const float4 v0 = *(const float4*)(Wb + r * 32 + (((2 * lg) ^ rsw) * 4));
      const float4 v1 = *(const float4*)(Wb + r * 32 + (((2 * lg + 1) ^ rsw) * 4));
      short8_t bh, bl;
      {
        const float f8[8] = {v0.x, v0.y, v0.z, v0.w, v1.x, v1.y, v1.z, v1.w};
#pragma unroll
        for (int e = 0; e < 8; ++e) {
          ushort h, lo;
          tsplit(f8[e], h, lo);
          bh[e] = (short)h;
          bl[e] = (short)lo;
        }
      }
#pragma unroll
      for (int mi = 0; mi < 4; ++mi) {
        acc[mi][ni] = __builtin_amdgcn_mfma_f32_16x16x32_bf16(ah[mi], bh, acc[mi][ni], 0, 0, 0);
        acc[mi][ni] = __builtin_amdgcn_mfma_f32_16x16x32_bf16(al[mi], bh, acc[mi][ni], 0, 0, 0);
        acc[mi][ni] = __builtin_amdgcn_mfma_f32_16x16x32_bf16(ah[mi], bl, acc[mi][ni], 0, 0, 0);
      }
    }
    asm volatile("s_waitcnt lgkmcnt(0)" ::: "memory");  // B reads retired
    __builtin_amdgcn_sched_barrier(0);
    if (l == 0) atomicAdd(&cns[slot], 1);
    slot = (slot == 2) ? 0 : slot + 1;
  }

  float* Pd = P + (size_t)s * 128 * N + n0 + 64 * wn;
#pragma unroll
  for (int mi = 0; mi < 4; ++mi)
#pragma unroll
    for (int ni = 0; ni < 4; ++ni) {
#pragma unroll
      for (int jj = 0; jj < 4; ++jj) {
        const int m = 64 * wm + 16 * mi + 4 * lg + jj;
        Pd[(size_t)m * N + 16 * ni + lr] = acc[mi][ni][jj];
      }
    }
}

// ---------------- small-K GEMM (round-8): P[s] = X * W^T --------------------
#define KSTEP 32
__global__ __launch_bounds__(256, 2) void k_gemm(const ushort* __restrict__ Ap,
                                                 const float* __restrict__ W, int ldw,
                                                 float* __restrict__ P,
                                                 int N, int Ks) {
  __shared__ ushort Ws[2][2][4][128][8];   // 32 KB

  const int n0   = blockIdx.x * 128;
  const int s    = blockIdx.z;
  const int kbeg = s * Ks;
  const int t    = threadIdx.x;
  const int l    = t & 63;
  const int w    = t >> 6;
  const int wm   = w >> 1;
  const int wn   = w & 1;
  const int lr   = l & 15;
  const int lg   = l >> 4;

  f32x4 acc[4][4];
#pragma unroll
  for (int mi = 0; mi < 4; ++mi)
#pragma unroll
    for (int ni = 0; ni < 4; ++ni) acc[mi][ni] = (f32x4)(0.0f);

  const int srow = t >> 3;
  const int sk16 = t & 7;
  const int skb  = sk16 >> 1;
  const int se0  = (sk16 & 1) * 4;
  const float* pWg = W + (size_t)(n0 + srow) * ldw + kbeg + sk16 * 4;

  const ushort* pAc = Ap + (size_t)(kbeg >> 5) * 8192;
  const int arow = 64 * wm + lr;
  const int brow = 64 * wn + lr;

  const int nIter = Ks / KSTEP;
  float4 wv[4];

#pragma unroll
  for (int r = 0; r < 4; ++r)
    wv[r] = *(const float4*)(pWg + (size_t)(r * 32) * ldw);
#pragma unroll
  for (int r = 0; r < 4; ++r) {
    ushort4 h4, l4;
    splitbf(wv[r].x, h4.x, l4.x); splitbf(wv[r].y, h4.y, l4.y);
    splitbf(wv[r].z, h4.z, l4.z); splitbf(wv[r].w, h4.w, l4.w);
    *(ushort4*)&Ws[0][0][skb][srow + 32 * r][se0] = h4;
    *(ushort4*)&Ws[0][1][skb][srow + 32 * r][se0] = l4;
  }
  __syncthreads();

  for (int j = 0; j < nIter; ++j) {
    const int bi = j & 1;
    const bool more = (j + 1 < nIter);

    const ushort* pAj = pAc + (size_t)j * 8192;
    short8_t ah[4], al[4];
#pragma unroll
    for (int mi = 0; mi < 4; ++mi) {
      const size_t fo = (size_t)lg * 1024 + (size_t)(arow + 16 * mi) * 8;
      ah[mi] = *(const short8_t*)(pAj + fo);
      al[mi] = *(const short8_t*)(pAj + 4096 + fo);
    }
    if (more) {
      const size_t ko = (size_t)(j + 1) * KSTEP;
#pragma unroll
      for (int r = 0; r < 4; ++r)
        wv[r] = *(const float4*)(pWg + ko + (size_t)(r * 32) * ldw);
    }
    short8_t bh[4], bl[4];
#pragma unroll
    for (int ni = 0; ni < 4; ++ni) {
      bh[ni] = *(const short8_t*)&Ws[bi][0][lg][brow + 16 * ni][0];
      bl[ni] = *(const short8_t*)&Ws[bi][1][lg][brow + 16 * ni][0];
    }
#pragma unroll
    for (int mi = 0; mi < 4; ++mi)
#pragma unroll
      for (int ni = 0; ni < 4; ++ni) {
        acc[mi][ni] = __builtin_amdgcn_mfma_f32_16x16x32_bf16(ah[mi], bh[ni], acc[mi][ni], 0, 0, 0);
        acc[mi][ni] = __builtin_amdgcn_mfma_f32_16x16x32_bf16(al[mi], bh[ni], acc[mi][ni], 0, 0, 0);
        acc[mi][ni] = __builtin_amdgcn_mfma_f32_16x16x32_bf16(ah[mi], bl[ni], acc[mi][ni], 0, 0, 0);
      }
    if (more) {
#pragma unroll
      for (int r = 0; r < 4; ++r) {
        ushort4 h4, l4;
        splitbf(wv[r].x, h4.x, l4.x); splitbf(wv[r].y, h4.y, l4.y);
        splitbf(wv[r].z, h4.z, l4.z); splitbf(wv[r].w, h4.w, l4.w);
        *(ushort4*)&Ws[bi ^ 1][0][skb][srow + 32 * r][se0] = h4;
        *(ushort4*)&Ws[bi ^ 1][1][skb][srow + 32 * r][se0] = l4;
      }
    }
    __syncthreads();
  }

  float* Pd = P + (size_t)s * 128 * N + n0 + 64 * wn;
#pragma unroll
  for (int mi = 0; mi < 4; ++mi)
#pragma unroll
    for (int ni = 0; ni < 4; ++ni) {
#pragma unroll
      for (int jj = 0; jj < 4; ++jj) {
        const int m = 64 * wm + 16 * mi + 4 * lg + jj;
        Pd[(size_t)m * N + 16 * ni + lr] = acc[mi][ni][jj];
      }
    }
}

// ---------------- reduce partials + epilogues -------------------------------
__global__ __launch_bounds__(256) void k_reduce(const float* __restrict__ P,
                                                float* __restrict__ Y,
                                                ushort* __restrict__ Yp,
                                                int MN, int N, int S, int ep,
                                                const float* __restrict__ bias) {
  int i = (blockIdx.x * 256 + threadIdx.x) * 4;
  if (i >= MN) return;
  float4 v = *(const float4*)&P[i];
  for (int s = 1; s < S; ++s) {
    float4 p = *(const float4*)&P[(size_t)s * MN + i];
    v.x += p.x; v.y += p.y; v.z += p.z; v.w += p.w;
  }
  int n = i % N;
  int l = i / N;
  if (ep & 1) {
    const float4 b = *(const float4*)&bias[n];
    v.x = softplusf_(v.x + b.x);
    v.y = softplusf_(v.y + b.y);
    v.z = softplusf_(v.z + b.z);
    v.w = softplusf_(v.w + b.w);
  }
  if (ep & 4) *(float4*)&Y[i] = v;
  if (ep & 2) {
    ushort4 h4, l4;
    splitbf(v.x, h4.x, l4.x);
    splitbf(v.y, h4.y, l4.y);
    splitbf(v.z, h4.z, l4.z);
    splitbf(v.w, h4.w, l4.w);
    size_t o = poff(l, n);
    *(ushort4*)&Yp[o] = h4;
    *(ushort4*)&Yp[o + 4096] = l4;
  }
}

__global__ __launch_bounds__(256) void k_reduceA(const float* __restrict__ P,
                                                 float* __restrict__ Y, int MN) {
  int g = blockIdx.y;
  int i = (blockIdx.x * 256 + threadIdx.x) * 4;
  if (i >= MN) return;
  const float* Pp = P + (size_t)g * 8 * MN;
  float4 v = *(const float4*)&Pp[i];
  for (int s = 1; s < 8; ++s) {
    float4 p = *(const float4*)&Pp[(size_t)s * MN + i];
    v.x += p.x; v.y += p.y; v.z += p.z; v.w += p.w;
  }
  *(float4*)&Y[(size_t)g * MN + i] = v;
}

// ---------------- depthwise causal conv (K=4) + silu + packed split ---------
__global__ __launch_bounds__(256) void k_conv_silu(const float* __restrict__ xz,
                                                   const float* __restrict__ cw,
                                                   const float* __restrict__ cb,
                                                   float* __restrict__ xc,
                                                   ushort* __restrict__ xcp,
                                                   int DI, int lg2DI) {
  int i = blockIdx.x * 256 + threadIdx.x;  // over 128*DI
  int l = i >> lg2DI;
  int d = i & (DI - 1);
  const float4 w = *(const float4*)&cw[d * 4];
  const float* xr = xz + d;
  int ld = 2 * DI;
  float s = cb[d];
  s += w.w * xr[l * ld];
  if (l >= 1) s += w.z * xr[(l - 1) * ld];
  if (l >= 2) s += w.y * xr[(l - 2) * ld];
  if (l >= 3) s += w.x * xr[(l - 3) * ld];
  float v = s * sigmoidf_(s);
  xc[i] = v;
  ushort h, lo;
  splitbf(v, h, lo);
  size_t o = poff(l, d);
  xcp[o] = h;
  xcp[o + 4096] = lo;
}

// ---------------- selective scan + fused gate: packed output ----------------
__global__ __launch_bounds__(256) void k_scan(const float* __restrict__ dt,
                                              const float* __restrict__ xc,
                                              const float* __restrict__ dbc,
                                              const float* __restrict__ A_log,
                                              const float* __restrict__ Dp,
                                              const float* __restrict__ xz,
                                              ushort* __restrict__ yp,
                                              int DI, int DTR) {
  __shared__ float cs[4][32][65];
  const int wid = threadIdx.x >> 6;
  const int n   = threadIdx.x & 63;
  const int d   = blockIdx.x * 4 + wid;
  const int du  = __builtin_amdgcn_readfirstlane(d);
  const float A  = -__expf(A_log[(size_t)du * 64 + n]);
  const float Dd = Dp[du];
  const int ldbc = DTR + 128;
  const float* Bp = dbc + DTR + n;
  const float* Cp = dbc + DTR + 64 + n;
  float h = 0.0f;
  for (int l0 = 0; l0 < 128; l0 += 32) {
#pragma unroll 8
    for (int l = l0; l < l0 + 32; ++l) {
      float dtv = dt[(size_t)l * DI + du];
      float xcv = xc[(size_t)l * DI + du];
      float dA  = __expf(dtv * A);
      float bx  = dtv * xcv;
      h = fmaf(dA, h, bx * Bp[(size_t)l * ldbc]);
      cs[wid][l - l0][n] = h * Cp[(size_t)l * ldbc];
    }
    __syncthreads();
    const int r = n & 31, hf = n >> 5;
    float ssum = 0.0f;
#pragma unroll
    for (int j = 0; j < 32; ++j) ssum += cs[wid][r][hf * 32 + j];
    ssum += __shfl_xor(ssum, 32, 64);
    if (n < 32) {
      int ll = l0 + r;
      float xcv = xc[(size_t)ll * DI + du];
      float yv  = ssum + xcv * Dd;
      float z   = xz[(size_t)ll * 2 * DI + DI + du];
      float v   = yv * (z * sigmoidf_(z));
      ushort hh, lo;
      splitbf(v, hh, lo);
      size_t o = poff(ll, du);
      yp[o] = hh;
      yp[o + 4096] = lo;
    }
    __syncthreads();
  }
}

// ---------------------------------------------------------------------------
struct GemmCtx {
  float* part;
  float* part2;
  long long cap;
};

static inline void reduce_stage(float* dstF, ushort* dstP, int N, int S, int ep,
                                const float* bias, const GemmCtx& cx,
                                hipStream_t stream) {
  const int MN = 128 * N;
  const int rb = (MN / 4 + 255) / 256;
  if (S <= 32) {
    k_reduce<<<rb, 256, 0, stream>>>(cx.part, dstF, dstP, MN, N, S, ep, bias);
  } else {
    k_reduceA<<<dim3(rb, S / 8), 256, 0, stream>>>(cx.part, cx.part2, MN);
    k_reduce<<<rb, 256, 0, stream>>>(cx.part2, dstF, dstP, MN, N, S / 8, ep, bias);
  }
}

// small-K GEMM path (x_proj / dt_proj)
static inline void gemmS(const ushort* Ap, const float* W, int ldw,
                         float* dstF, ushort* dstP,
                         int N, int K, int Sdes, int ep,
                         const float* bias, const GemmCtx& cx, hipStream_t stream) {
  int S = Sdes;
  if (S > K / KSTEP) S = K / KSTEP;
  if (S < 1) S = 1;
  while (S > 1 && (long long)S * 128 * N > cx.cap) S >>= 1;
  const int Ks = K / S;
  const bool direct = (S == 1 && ep == 4);
  dim3 g(N / 128, 1, S);
  k_gemm<<<g, 256, 0, stream>>>(Ap, W, ldw, direct ? dstF : cx.part, N, Ks);
  if (!direct) reduce_stage(dstF, dstP, N, S, ep, bias, cx, stream);
}

// weight-heavy GEMM path (in_proj / out_proj) — producer/consumer kernel
static inline void gemmW(const ushort* Ap, const float* W, int ldw,
                         float* dstF, ushort* dstP,
                         int N, int K, int Sdes, int ep,
                         const float* bias, const GemmCtx& cx, hipStream_t stream) {
  int S = Sdes;
  if (S > K / (4 * KWS)) S = K / (4 * KWS);   // keep nIter >= 4
  if (S < 1) S = 1;
  while (S > 1 && (long long)S * 128 * N > cx.cap) S >>= 1;
  const int Ks = K / S;
  const bool direct = (S == 1 && ep == 4);
  dim3 g(N / 128, 1, S);
  k_gemmWPC<<<g, 512, 0, stream>>>(Ap, W, ldw, direct ? dstF : cx.part, N, Ks);
  if (!direct) reduce_stage(dstF, dstP, N, S, ep, bias, cx, stream);
}

extern "C" void kernel_launch(void* const* d_in, const int* in_sizes, int n_in,
                              void* d_out, int out_size, void* d_ws, size_t ws_size,
                              hipStream_t stream) {
  const float* pe        = (const float*)d_in[0];
  const float* to_cond_w = (const float*)d_in[1];
  const float* to_cond_b = (const float*)d_in[2];
  const float* condition = (const float*)d_in[3];
  const int o = (in_sizes[4] == 1) ? 5 : 4;
  const float* m1_in_proj  = (const float*)d_in[o + 0];
  const float* m1_conv_w   = (const float*)d_in[o + 1];
  const float* m1_conv_b   = (const float*)d_in[o + 2];
  const float* m1_x_proj   = (const float*)d_in[o + 3];
  const float* m1_dt_w     = (const float*)d_in[o + 4];
  const float* m1_dt_b     = (const float*)d_in[o + 5];
  const float* m1_A_log    = (const float*)d_in[o + 6];
  const float* m1_D        = (const float*)d_in[o + 7];
  const float* m1_out_proj = (const float*)d_in[o + 8];
  const float* m2_in_proj  = (const float*)d_in[o + 9];
  const float* m2_conv_w   = (const float*)d_in[o + 10];
  const float* m2_conv_b   = (const float*)d_in[o + 11];
  const float* m2_x_proj   = (const float*)d_in[o + 12];
  const float* m2_dt_w     = (const float*)d_in[o + 13];
  const float* m2_dt_b     = (const float*)d_in[o + 14];
  const float* m2_A_log    = (const float*)d_in[o + 15];
  const float* m2_D        = (const float*)d_in[o + 16];
  const float* m2_out_proj = (const float*)d_in[o + 17];

  float* ws = (float*)d_ws;
  float*  xz   = ws;                        // 2,097,152
  float*  xc   = ws + 2097152;              // 1,048,576
  float*  dbc  = ws + 3145728;              //    49,152
  float*  dtb  = ws + 3194880;              // 1,048,576
  ushort* x0p  = (ushort*)(ws + 5292032);   //   262,144 f (hi+lo packed)
  ushort* xcp  = (ushort*)(ws + 5554176);   // 1,048,576 f
  ushort* dbcp = (ushort*)(ws + 6602752);   //    49,152 f
  ushort* ybp  = (ushort*)(ws + 6651904);   // 1,048,576 f
  ushort* midp = (ushort*)(ws + 7700480);   //   262,144 f
  float*  part2 = ws + 7962624;             //   786,432
  float*  part  = ws + 8749056;             // rest

  GemmCtx cx;
  cx.part = part;
  cx.part2 = part2;
  cx.cap = (long long)(ws_size / 4) - 8749056;
  if (cx.cap < 0) cx.cap = 0;

  k_prep<<<1024, 256, 0, stream>>>(pe, to_cond_w, to_cond_b, condition, x0p);

  // ---------------- mamba block 1: DI=4096, DTR=128 ----------------
  gemmW(x0p, m1_in_proj, 2048, xz, nullptr, 8192, 2048, 8, 4, nullptr, cx, stream);   // 512 blk
  k_conv_silu<<<(128 * 4096) / 256, 256, 0, stream>>>(xz, m1_conv_w, m1_conv_b,
                                                      xc, xcp, 4096, 12);
  gemmS(xcp, m1_x_proj, 4096, dbc, dbcp, 256, 4096, 128, 6, nullptr, cx, stream);
  gemmS(dbcp, m1_dt_w, 128, dtb, nullptr, 4096, 128, 4, 5, m1_dt_b, cx, stream);
  k_scan<<<1024, 256, 0, stream>>>(dtb, xc, dbc, m1_A_log, m1_D, xz, ybp, 4096, 128);
  gemmW(ybp, m1_out_proj, 4096, nullptr, midp, 2048, 4096, 32, 2, nullptr, cx, stream); // 512 blk

  // ---------------- mamba block 2: DI=8192, DTR=256 ----------------
  gemmW(midp, m2_in_proj, 2048, xz, nullptr, 16384, 2048, 4, 4, nullptr, cx, stream); // 512 blk
  k_conv_silu<<<(128 * 8192) / 256, 256, 0, stream>>>(xz, m2_conv_w, m2_conv_b,
                                                      xc, xcp, 8192, 13);
  gemmS(xcp, m2_x_proj, 8192, dbc, dbcp, 384, 8192, 128, 6, nullptr, cx, stream);
  gemmS(dbcp, m2_dt_w, 256, dtb, nullptr, 8192, 256, 4, 5, m2_dt_b, cx, stream);
  k_scan<<<2048, 256, 0, stream>>>(dtb, xc, dbc, m2_A_log, m2_D, xz, ybp, 8192, 256);
  gemmW(ybp, m2_out_proj, 8192, (float*)d_out, nullptr, 4096, 8192, 16, 4, nullptr, cx, stream); // 512 blk
}

// Round 24
// 328.912 us; speedup vs baseline: 1.0091x; 1.0022x over previous
//
#include <hip/hip_runtime.h>
#include <hip/hip_bf16.h>
#include <math.h>

// ---------------------------------------------------------------------------
// VaryMambaModel: batch=1, L=128
//   PRE_D=2048, D=4096, N=64, K=4, DI1=4096, DI2=8192, DTR1=128, DTR2=256
// Round 23: producer/consumer champion (329.6 us) + packed truncation-split
// in the consumer via v_perm_b32 (__builtin_amdgcn_perm): 24 VALU ops per 8
// floats vs ~128, bit-exact same bh/bl fragments. Sync protocol, producers,
// and all other kernels byte-identical to the validated champion.
// ---------------------------------------------------------------------------

typedef __attribute__((ext_vector_type(8))) short short8_t;   // 8 bf16
typedef __attribute__((ext_vector_type(4))) float f32x4;
typedef __attribute__((ext_vector_type(4))) unsigned int u32x4;

__device__ __forceinline__ float sigmoidf_(float x) {
  return 1.0f / (1.0f + __expf(-x));
}
__device__ __forceinline__ float softplusf_(float x) {
  return fmaxf(x, 0.0f) + log1pf(expf(-fabsf(x)));
}
__device__ __forceinline__ void splitbf(float f, ushort& h, ushort& lo) {
  __hip_bfloat16 hb = __float2bfloat16(f);
  h = *reinterpret_cast<ushort*>(&hb);
  float hf = __bfloat162float(hb);
  __hip_bfloat16 lb = __float2bfloat16(f - hf);
  lo = *reinterpret_cast<ushort*>(&lb);
}
// truncation split: f = h + r exactly; lo = trunc_bf16(r)
__device__ __forceinline__ void tsplit(float f, ushort& h, ushort& lo) {
  unsigned u = __float_as_uint(f);
  h = (ushort)(u >> 16);
  float r = f - __uint_as_float(u & 0xFFFF0000u);
  lo = (ushort)(__float_as_uint(r) >> 16);
}
// pack hi-16 of two f32 into one dword: low16 = bits(a)>>16, high16 = bits(b)>>16
__device__ __forceinline__ unsigned packhi(float a, float b) {
  return __builtin_amdgcn_perm(__float_as_uint(b), __float_as_uint(a), 0x07060302u);
}
// packed layout (per 32-k chunk, 8192 ushorts): [hl][kb=(k>>3)&3][row][k&7]
__device__ __forceinline__ size_t poff(int l, int d) {
  return (size_t)(d >> 5) * 8192 + (size_t)((d >> 3) & 3) * 1024 +
         (size_t)l * 8 + (d & 7);
}
// 16B/lane global->LDS DMA (linear dest: base + lane*16)
__device__ __forceinline__ void g2l16(const float* g, float* lp) {
  __builtin_amdgcn_global_load_lds(
      (const __attribute__((address_space(1))) unsigned int*)g,
      (__attribute__((address_space(3))) unsigned int*)lp, 16, 0, 0);
}

// ---------------- prep: x0 = pe + cond*to_cond_w + to_cond_b -> packed ------
__global__ __launch_bounds__(256) void k_prep(const float* __restrict__ pe,
                                              const float* __restrict__ cw,
                                              const float* __restrict__ cb,
                                              const float* __restrict__ cond,
                                              ushort* __restrict__ xp) {
  int i = blockIdx.x * 256 + threadIdx.x;  // 128*2048
  int d = i & 2047;
  int l = i >> 11;
  float v = pe[i] + cond[0] * cw[d] + cb[d];
  ushort h, lo;
  splitbf(v, h, lo);
  size_t o = poff(l, d);
  xp[o] = h;
  xp[o + 4096] = lo;
}

// ---------------- producer/consumer weight GEMM -----------------------------
// Tile 128m x 128n, 512 thr = 8 waves. Waves 4-7: producers (wave p stages
// rows 32p..32p+31 of each 32k chunk via 4x g2l16, 3-deep ring). Waves 0-3:
// consumers (2x2, 64m x 64n each). Lane-0-guarded monotonic counters.
#define KWS 32
__global__ __launch_bounds__(512, 2) void k_gemmWPC(const ushort* __restrict__ Ap,
                                                    const float* __restrict__ W, int ldw,
                                                    float* __restrict__ P,
                                                    int N, int Ks) {
  __shared__ float ring[3][128][32];   // 48 KB
  __shared__ int rdy[3];
  __shared__ int cns[3];

  const int n0   = blockIdx.x * 128;
  const int s    = blockIdx.z;
  const int kbeg = s * Ks;
  const int t    = threadIdx.x;
  const int l    = t & 63;
  const int w    = t >> 6;          // 0..7
  const int nIter = Ks / KWS;

  if (t < 3) { rdy[t] = 0; cns[t] = 0; }
  __syncthreads();

  if (w >= 4) {
    // ================= PRODUCER (wave p = w-4) =================
    const int p = w - 4;
    const int grow = l >> 3;
    const int gg   = (l & 7) ^ (grow & 7);
    const float* gW[4];
#pragma unroll
    for (int i = 0; i < 4; ++i)
      gW[i] = W + (size_t)(n0 + 32 * p + 8 * i + grow) * ldw + kbeg + gg * 4;
    float* ldst[4];
#pragma unroll
    for (int i = 0; i < 4; ++i)
      ldst[i] = &ring[0][0][0] + (32 * p + 8 * i) * 32;

    volatile int* vcns = cns;
    int slot = 0;
    for (int j = 0; j < nIter; ++j) {
      if (j >= 3) {
        const int tgt = 4 * (j / 3);           // chunk j-3 fully consumed
        while (vcns[slot] < tgt) __builtin_amdgcn_s_sleep(2);
        __builtin_amdgcn_sched_barrier(0);
      }
#pragma unroll
      for (int i = 0; i < 4; ++i)
        g2l16(gW[i] + (size_t)j * KWS, ldst[i] + slot * 128 * 32);
      if (j >= 1) {
        asm volatile("s_waitcnt vmcnt(4)" ::: "memory");   // chunk j-1 landed
        __builtin_amdgcn_sched_barrier(0);
        if (l == 0) atomicAdd(&rdy[(slot == 0) ? 2 : slot - 1], 1);
      }
      slot = (slot == 2) ? 0 : slot + 1;
    }
    asm volatile("s_waitcnt vmcnt(0)" ::: "memory");
    __builtin_amdgcn_sched_barrier(0);
    if (l == 0) atomicAdd(&rdy[(nIter - 1) % 3], 1);
    return;
  }

  // ================= CONSUMER (wave w = 0..3) =================
  const int wm = w >> 1;
  const int wn = w & 1;
  const int lr = l & 15;
  const int lg = l >> 4;

  f32x4 acc[4][4];
#pragma unroll
  for (int mi = 0; mi < 4; ++mi)
#pragma unroll
    for (int ni = 0; ni < 4; ++ni) acc[mi][ni] = (f32x4)(0.0f);

  const ushort* pA0 = Ap + (size_t)(kbeg >> 5) * 8192;
  const int arow = 64 * wm + lr;
  const int rsw  = lr & 7;
  volatile int* vrdy = rdy;

  int slot = 0;
  for (int j = 0; j < nIter; ++j) {
    // A fragments for this chunk (overlap the spin)
    const ushort* pAj = pA0 + (size_t)j * 8192;
    short8_t ah[4], al[4];
#pragma unroll
    for (int mi = 0; mi < 4; ++mi) {
      const size_t fo = (size_t)lg * 1024 + (size_t)(arow + 16 * mi) * 8;
      ah[mi] = *(const short8_t*)(pAj + fo);
      al[mi] = *(const short8_t*)(pAj + 4096 + fo);
    }
    const int tgt = 4 * (j / 3 + 1);           // chunk j fully published
    while (vrdy[slot] < tgt) __builtin_amdgcn_s_sleep(2);
    __builtin_amdgcn_sched_barrier(0);

    const float* Wb = &ring[slot][0][0];
#pragma unroll
    for (int ni = 0; ni < 4; ++ni) {
      const int r = 64 * wn + 16 * ni + lr;
      const float4 v0 = *(const float4*)(Wb + r * 32 + (((2 * lg) ^ rsw) * 4));
      const float4 v1 = *(const float4*)(Wb + r * 32 + (((2 * lg + 1) ^ rsw) * 4));
      // packed truncation split (bit-exact vs tsplit): hi via v_perm, residual
      // r = f - (f & 0xFFFF0000), lo via v_perm on residual pairs.
      short8_t bh, bl;
      {
        const float f8[8] = {v0.x, v0.y, v0.z, v0.w, v1.x, v1.y, v1.z, v1.w};
        float r8[8];
#pragma unroll
        for (int e = 0; e < 8; ++e)
          r8[e] = f8[e] - __uint_as_float(__float_as_uint(f8[e]) & 0xFFFF0000u);
        u32x4 uh, ul;
        uh.x = packhi(f8[0], f8[1]); uh.y = packhi(f8[2], f8[3]);
        uh.z = packhi(f8[4], f8[5]); uh.w = packhi(f8[6], f8[7]);
        ul.x = packhi(r8[0], r8[1]); ul.y = packhi(r8[2], r8[3]);
        ul.z = packhi(r8[4], r8[5]); ul.w = packhi(r8[6], r8[7]);
        bh = *reinterpret_cast<short8_t*>(&uh);
        bl = *reinterpret_cast<short8_t*>(&ul);
      }
#pragma unroll
      for (int mi = 0; mi < 4; ++mi) {
        acc[mi][ni] = __builtin_amdgcn_mfma_f32_16x16x32_bf16(ah[mi], bh, acc[mi][ni], 0, 0, 0);
        acc[mi][ni] = __builtin_amdgcn_mfma_f32_16x16x32_bf16(al[mi], bh, acc[mi][ni], 0, 0, 0);
        acc[mi][ni] = __builtin_amdgcn_mfma_f32_16x16x32_bf16(ah[mi], bl, acc[mi][ni], 0, 0, 0);
      }
    }
    asm volatile("s_waitcnt lgkmcnt(0)" ::: "memory");  // B reads retired
    __builtin_amdgcn_sched_barrier(0);
    if (l == 0) atomicAdd(&cns[slot], 1);
    slot = (slot == 2) ? 0 : slot + 1;
  }

  float* Pd = P + (size_t)s * 128 * N + n0 + 64 * wn;
#pragma unroll
  for (int mi = 0; mi < 4; ++mi)
#pragma unroll
    for (int ni = 0; ni < 4; ++ni) {
#pragma unroll
      for (int jj = 0; jj < 4; ++jj) {
        const int m = 64 * wm + 16 * mi + 4 * lg + jj;
        Pd[(size_t)m * N + 16 * ni + lr] = acc[mi][ni][jj];
      }
    }
}

// ---------------- small-K GEMM (round-8): P[s] = X * W^T --------------------
#define KSTEP 32
__global__ __launch_bounds__(256, 2) void k_gemm(const ushort* __restrict__ Ap,
                                                 const float* __restrict__ W, int ldw,
                                                 float* __restrict__ P,
                                                 int N, int Ks) {
  __shared__ ushort Ws[2][2][4][128][8];   // 32 KB

  const int n0   = blockIdx.x * 128;
  const int s    = blockIdx.z;
  const int kbeg = s * Ks;
  const int t    = threadIdx.x;
  const int l    = t & 63;
  const int w    = t >> 6;
  const int wm   = w >> 1;
  const int wn   = w & 1;
  const int lr   = l & 15;
  const int lg   = l >> 4;

  f32x4 acc[4][4];
#pragma unroll
  for (int mi = 0; mi < 4; ++mi)
#pragma unroll
    for (int ni = 0; ni < 4; ++ni) acc[mi][ni] = (f32x4)(0.0f);

  const int srow = t >> 3;
  const int sk16 = t & 7;
  const int skb  = sk16 >> 1;
  const int se0  = (sk16 & 1) * 4;
  const float* pWg = W + (size_t)(n0 + srow) * ldw + kbeg + sk16 * 4;

  const ushort* pAc = Ap + (size_t)(kbeg >> 5) * 8192;
  const int arow = 64 * wm + lr;
  const int brow = 64 * wn + lr;

  const int nIter = Ks / KSTEP;
  float4 wv[4];

#pragma unroll
  for (int r = 0; r < 4; ++r)
    wv[r] = *(const float4*)(pWg + (size_t)(r * 32) * ldw);
#pragma unroll
  for (int r = 0; r < 4; ++r) {
    ushort4 h4, l4;
    splitbf(wv[r].x, h4.x, l4.x); splitbf(wv[r].y, h4.y, l4.y);
    splitbf(wv[r].z, h4.z, l4.z); splitbf(wv[r].w, h4.w, l4.w);
    *(ushort4*)&Ws[0][0][skb][srow + 32 * r][se0] = h4;
    *(ushort4*)&Ws[0][1][skb][srow + 32 * r][se0] = l4;
  }
  __syncthreads();

  for (int j = 0; j < nIter; ++j) {
    const int bi = j & 1;
    const bool more = (j + 1 < nIter);

    const ushort* pAj = pAc + (size_t)j * 8192;
    short8_t ah[4], al[4];
#pragma unroll
    for (int mi = 0; mi < 4; ++mi) {
      const size_t fo = (size_t)lg * 1024 + (size_t)(arow + 16 * mi) * 8;
      ah[mi] = *(const short8_t*)(pAj + fo);
      al[mi] = *(const short8_t*)(pAj + 4096 + fo);
    }
    if (more) {
      const size_t ko = (size_t)(j + 1) * KSTEP;
#pragma unroll
      for (int r = 0; r < 4; ++r)
        wv[r] = *(const float4*)(pWg + ko + (size_t)(r * 32) * ldw);
    }
    short8_t bh[4], bl[4];
#pragma unroll
    for (int ni = 0; ni < 4; ++ni) {
      bh[ni] = *(const short8_t*)&Ws[bi][0][lg][brow + 16 * ni][0];
      bl[ni] = *(const short8_t*)&Ws[bi][1][lg][brow + 16 * ni][0];
    }
#pragma unroll
    for (int mi = 0; mi < 4; ++mi)
#pragma unroll
      for (int ni = 0; ni < 4; ++ni) {
        acc[mi][ni] = __builtin_amdgcn_mfma_f32_16x16x32_bf16(ah[mi], bh[ni], acc[mi][ni], 0, 0, 0);
        acc[mi][ni] = __builtin_amdgcn_mfma_f32_16x16x32_bf16(al[mi], bh[ni], acc[mi][ni], 0, 0, 0);
        acc[mi][ni] = __builtin_amdgcn_mfma_f32_16x16x32_bf16(ah[mi], bl[ni], acc[mi][ni], 0, 0, 0);
      }
    if (more) {
#pragma unroll
      for (int r = 0; r < 4; ++r) {
        ushort4 h4, l4;
        splitbf(wv[r].x, h4.x, l4.x); splitbf(wv[r].y, h4.y, l4.y);
        splitbf(wv[r].z, h4.z, l4.z); splitbf(wv[r].w, h4.w, l4.w);
        *(ushort4*)&Ws[bi ^ 1][0][skb][srow + 32 * r][se0] = h4;
        *(ushort4*)&Ws[bi ^ 1][1][skb][srow + 32 * r][se0] = l4;
      }
    }
    __syncthreads();
  }

  float* Pd = P + (size_t)s * 128 * N + n0 + 64 * wn;
#pragma unroll
  for (int mi = 0; mi < 4; ++mi)
#pragma unroll
    for (int ni = 0; ni < 4; ++ni) {
#pragma unroll
      for (int jj = 0; jj < 4; ++jj) {
        const int m = 64 * wm + 16 * mi + 4 * lg + jj;
        Pd[(size_t)m * N + 16 * ni + lr] = acc[mi][ni][jj];
      }
    }
}

// ---------------- reduce partials + epilogues -------------------------------
__global__ __launch_bounds__(256) void k_reduce(const float* __restrict__ P,
                                                float* __restrict__ Y,
                                                ushort* __restrict__ Yp,
                                                int MN, int N, int S, int ep,
                                                const float* __restrict__ bias) {
  int i = (blockIdx.x * 256 + threadIdx.x) * 4;
  if (i >= MN) return;
  float4 v = *(const float4*)&P[i];
  for (int s = 1; s < S; ++s) {
    float4 p = *(const float4*)&P[(size_t)s * MN + i];
    v.x += p.x; v.y += p.y; v.z += p.z; v.w += p.w;
  }
  int n = i % N;
  int l = i / N;
  if (ep & 1) {
    const float4 b = *(const float4*)&bias[n];
    v.x = softplusf_(v.x + b.x);
    v.y = softplusf_(v.y + b.y);
    v.z = softplusf_(v.z + b.z);
    v.w = softplusf_(v.w + b.w);
  }
  if (ep & 4) *(float4*)&Y[i] = v;
  if (ep & 2) {
    ushort4 h4, l4;
    splitbf(v.x, h4.x, l4.x);
    splitbf(v.y, h4.y, l4.y);
    splitbf(v.z, h4.z, l4.z);
    splitbf(v.w, h4.w, l4.w);
    size_t o = poff(l, n);
    *(ushort4*)&Yp[o] = h4;
    *(ushort4*)&Yp[o + 4096] = l4;
  }
}

__global__ __launch_bounds__(256) void k_reduceA(const float* __restrict__ P,
                                                 float* __restrict__ Y, int MN) {
  int g = blockIdx.y;
  int i = (blockIdx.x * 256 + threadIdx.x) * 4;
  if (i >= MN) return;
  const float* Pp = P + (size_t)g * 8 * MN;
  float4 v = *(const float4*)&Pp[i];
  for (int s = 1; s < 8; ++s) {
    float4 p = *(const float4*)&Pp[(size_t)s * MN + i];
    v.x += p.x; v.y += p.y; v.z += p.z; v.w += p.w;
  }
  *(float4*)&Y[(size_t)g * MN + i] = v;
}

// ---------------- depthwise causal conv (K=4) + silu + packed split ---------
__global__ __launch_bounds__(256) void k_conv_silu(const float* __restrict__ xz,
                                                   const float* __restrict__ cw,
                                                   const float* __restrict__ cb,
                                                   float* __restrict__ xc,
                                                   ushort* __restrict__ xcp,
                                                   int DI, int lg2DI) {
  int i = blockIdx.x * 256 + threadIdx.x;  // over 128*DI
  int l = i >> lg2DI;
  int d = i & (DI - 1);
  const float4 w = *(const float4*)&cw[d * 4];
  const float* xr = xz + d;
  int ld = 2 * DI;
  float s = cb[d];
  s += w.w * xr[l * ld];
  if (l >= 1) s += w.z * xr[(l - 1) * ld];
  if (l >= 2) s += w.y * xr[(l - 2) * ld];
  if (l >= 3) s += w.x * xr[(l - 3) * ld];
  float v = s * sigmoidf_(s);
  xc[i] = v;
  ushort h, lo;
  splitbf(v, h, lo);
  size_t o = poff(l, d);
  xcp[o] = h;
  xcp[o + 4096] = lo;
}

// ---------------- selective scan + fused gate: packed output ----------------
__global__ __launch_bounds__(256) void k_scan(const float* __restrict__ dt,
                                              const float* __restrict__ xc,
                                              const float* __restrict__ dbc,
                                              const float* __restrict__ A_log,
                                              const float* __restrict__ Dp,
                                              const float* __restrict__ xz,
                                              ushort* __restrict__ yp,
                                              int DI, int DTR) {
  __shared__ float cs[4][32][65];
  const int wid = threadIdx.x >> 6;
  const int n   = threadIdx.x & 63;
  const int d   = blockIdx.x * 4 + wid;
  const int du  = __builtin_amdgcn_readfirstlane(d);
  const float A  = -__expf(A_log[(size_t)du * 64 + n]);
  const float Dd = Dp[du];
  const int ldbc = DTR + 128;
  const float* Bp = dbc + DTR + n;
  const float* Cp = dbc + DTR + 64 + n;
  float h = 0.0f;
  for (int l0 = 0; l0 < 128; l0 += 32) {
#pragma unroll 8
    for (int l = l0; l < l0 + 32; ++l) {
      float dtv = dt[(size_t)l * DI + du];
      float xcv = xc[(size_t)l * DI + du];
      float dA  = __expf(dtv * A);
      float bx  = dtv * xcv;
      h = fmaf(dA, h, bx * Bp[(size_t)l * ldbc]);
      cs[wid][l - l0][n] = h * Cp[(size_t)l * ldbc];
    }
    __syncthreads();
    const int r = n & 31, hf = n >> 5;
    float ssum = 0.0f;
#pragma unroll
    for (int j = 0; j < 32; ++j) ssum += cs[wid][r][hf * 32 + j];
    ssum += __shfl_xor(ssum, 32, 64);
    if (n < 32) {
      int ll = l0 + r;
      float xcv = xc[(size_t)ll * DI + du];
      float yv  = ssum + xcv * Dd;
      float z   = xz[(size_t)ll * 2 * DI + DI + du];
      float v   = yv * (z * sigmoidf_(z));
      ushort hh, lo;
      splitbf(v, hh, lo);
      size_t o = poff(ll, du);
      yp[o] = hh;
      yp[o + 4096] = lo;
    }
    __syncthreads();
  }
}

// ---------------------------------------------------------------------------
struct GemmCtx {
  float* part;
  float* part2;
  long long cap;
};

static inline void reduce_stage(float* dstF, ushort* dstP, int N, int S, int ep,
                                const float* bias, const GemmCtx& cx,
                                hipStream_t stream) {
  const int MN = 128 * N;
  const int rb = (MN / 4 + 255) / 256;
  if (S <= 32) {
    k_reduce<<<rb, 256, 0, stream>>>(cx.part, dstF, dstP, MN, N, S, ep, bias);
  } else {
    k_reduceA<<<dim3(rb, S / 8), 256, 0, stream>>>(cx.part, cx.part2, MN);
    k_reduce<<<rb, 256, 0, stream>>>(cx.part2, dstF, dstP, MN, N, S / 8, ep, bias);
  }
}

// small-K GEMM path (x_proj / dt_proj)
static inline void gemmS(const ushort* Ap, const float* W, int ldw,
                         float* dstF, ushort* dstP,
                         int N, int K, int Sdes, int ep,
                         const float* bias, const GemmCtx& cx, hipStream_t stream) {
  int S = Sdes;
  if (S > K / KSTEP) S = K / KSTEP;
  if (S < 1) S = 1;
  while (S > 1 && (long long)S * 128 * N > cx.cap) S >>= 1;
  const int Ks = K / S;
  const bool direct = (S == 1 && ep == 4);
  dim3 g(N / 128, 1, S);
  k_gemm<<<g, 256, 0, stream>>>(Ap, W, ldw, direct ? dstF : cx.part, N, Ks);
  if (!direct) reduce_stage(dstF, dstP, N, S, ep, bias, cx, stream);
}

// weight-heavy GEMM path (in_proj / out_proj) — producer/consumer kernel
static inline void gemmW(const ushort* Ap, const float* W, int ldw,
                         float* dstF, ushort* dstP,
                         int N, int K, int Sdes, int ep,
                         const float* bias, const GemmCtx& cx, hipStream_t stream) {
  int S = Sdes;
  if (S > K / (4 * KWS)) S = K / (4 * KWS);   // keep nIter >= 4
  if (S < 1) S = 1;
  while (S > 1 && (long long)S * 128 * N > cx.cap) S >>= 1;
  const int Ks = K / S;
  const bool direct = (S == 1 && ep == 4);
  dim3 g(N / 128, 1, S);
  k_gemmWPC<<<g, 512, 0, stream>>>(Ap, W, ldw, direct ? dstF : cx.part, N, Ks);
  if (!direct) reduce_stage(dstF, dstP, N, S, ep, bias, cx, stream);
}

extern "C" void kernel_launch(void* const* d_in, const int* in_sizes, int n_in,
                              void* d_out, int out_size, void* d_ws, size_t ws_size,
                              hipStream_t stream) {
  const float* pe        = (const float*)d_in[0];
  const float* to_cond_w = (const float*)d_in[1];
  const float* to_cond_b = (const float*)d_in[2];
  const float* condition = (const float*)d_in[3];
  const int o = (in_sizes[4] == 1) ? 5 : 4;
  const float* m1_in_proj  = (const float*)d_in[o + 0];
  const float* m1_conv_w   = (const float*)d_in[o + 1];
  const float* m1_conv_b   = (const float*)d_in[o + 2];
  const float* m1_x_proj   = (const float*)d_in[o + 3];
  const float* m1_dt_w     = (const float*)d_in[o + 4];
  const float* m1_dt_b     = (const float*)d_in[o + 5];
  const float* m1_A_log    = (const float*)d_in[o + 6];
  const float* m1_D        = (const float*)d_in[o + 7];
  const float* m1_out_proj = (const float*)d_in[o + 8];
  const float* m2_in_proj  = (const float*)d_in[o + 9];
  const float* m2_conv_w   = (const float*)d_in[o + 10];
  const float* m2_conv_b   = (const float*)d_in[o + 11];
  const float* m2_x_proj   = (const float*)d_in[o + 12];
  const float* m2_dt_w     = (const float*)d_in[o + 13];
  const float* m2_dt_b     = (const float*)d_in[o + 14];
  const float* m2_A_log    = (const float*)d_in[o + 15];
  const float* m2_D        = (const float*)d_in[o + 16];
  const float* m2_out_proj = (const float*)d_in[o + 17];

  float* ws = (float*)d_ws;
  float*  xz   = ws;                        // 2,097,152
  float*  xc   = ws + 2097152;              // 1,048,576
  float*  dbc  = ws + 3145728;              //    49,152
  float*  dtb  = ws + 3194880;              // 1,048,576
  ushort* x0p  = (ushort*)(ws + 5292032);   //   262,144 f (hi+lo packed)
  ushort* xcp  = (ushort*)(ws + 5554176);   // 1,048,576 f
  ushort* dbcp = (ushort*)(ws + 6602752);   //    49,152 f
  ushort* ybp  = (ushort*)(ws + 6651904);   // 1,048,576 f
  ushort* midp = (ushort*)(ws + 7700480);   //   262,144 f
  float*  part2 = ws + 7962624;             //   786,432
  float*  part  = ws + 8749056;             // rest

  GemmCtx cx;
  cx.part = part;
  cx.part2 = part2;
  cx.cap = (long long)(ws_size / 4) - 8749056;
  if (cx.cap < 0) cx.cap = 0;

  k_prep<<<1024, 256, 0, stream>>>(pe, to_cond_w, to_cond_b, condition, x0p);

  // ---------------- mamba block 1: DI=4096, DTR=128 ----------------
  gemmW(x0p, m1_in_proj, 2048, xz, nullptr, 8192, 2048, 8, 4, nullptr, cx, stream);   // 512 blk
  k_conv_silu<<<(128 * 4096) / 256, 256, 0, stream>>>(xz, m1_conv_w, m1_conv_b,
                                                      xc, xcp, 4096, 12);
  gemmS(xcp, m1_x_proj, 4096, dbc, dbcp, 256, 4096, 128, 6, nullptr, cx, stream);
  gemmS(dbcp, m1_dt_w, 128, dtb, nullptr, 4096, 128, 4, 5, m1_dt_b, cx, stream);
  k_scan<<<1024, 256, 0, stream>>>(dtb, xc, dbc, m1_A_log, m1_D, xz, ybp, 4096, 128);
  gemmW(ybp, m1_out_proj, 4096, nullptr, midp, 2048, 4096, 32, 2, nullptr, cx, stream); // 512 blk

  // ---------------- mamba block 2: DI=8192, DTR=256 ----------------
  gemmW(midp, m2_in_proj, 2048, xz, nullptr, 16384, 2048, 4, 4, nullptr, cx, stream); // 512 blk
  k_conv_silu<<<(128 * 8192) / 256, 256, 0, stream>>>(xz, m2_conv_w, m2_conv_b,
                                                      xc, xcp, 8192, 13);
  gemmS(xcp, m2_x_proj, 8192, dbc, dbcp, 384, 8192, 128, 6, nullptr, cx, stream);
  gemmS(dbcp, m2_dt_w, 256, dtb, nullptr, 8192, 256, 4, 5, m2_dt_b, cx, stream);
  k_scan<<<2048, 256, 0, stream>>>(dtb, xc, dbc, m2_A_log, m2_D, xz, ybp, 8192, 256);
  gemmW(ybp, m2_out_proj, 8192, (float*)d_out, nullptr, 4096, 8192, 16, 4, nullptr, cx, stream); // 512 blk
}